// Round 9
// baseline (208.554 us; speedup 1.0000x reference)
//
#include <hip/hip_runtime.h>
#include <stdint.h>

typedef unsigned short u16;
typedef __attribute__((ext_vector_type(8))) __bf16 bf16x8;
typedef __attribute__((ext_vector_type(4))) float f32x4;

#define MAXMT 40
#define N_TOK 2048
#define DDIM 1024
#define FDIM 1024

#define DEV static __device__ __forceinline__

DEV float bf2f(u16 u) {
    union { uint32_t i; float f; } v;
    v.i = ((uint32_t)u) << 16;
    return v.f;
}
DEV u16 f2bf(float f) {
    union { float f; uint32_t i; } v;
    v.f = f;
    uint32_t x = v.i;
    return (u16)((x + 0x7fffu + ((x >> 16) & 1u)) >> 16);  // RNE
}

// async global->LDS, 16B per lane; lds base wave-uniform, HW writes lane i at base+16*i
DEV void async_copy16(const u16* gsrc, u16* ldst) {
    __builtin_amdgcn_global_load_lds(
        (const __attribute__((address_space(1))) void*)(uintptr_t)gsrc,
        (__attribute__((address_space(3))) void*)(uint32_t)(uintptr_t)ldst,
        16, 0, 0);
}

// per-block dtype sniff: sample first 256 u16 of tensor; fp32-reinterpreted data has
// ~36% wild exponent fields, bf16 ~0%. Returns 1 => fp32.
DEV int sniff_fp(const void* p, int tid, int* scnt) {
    if (tid == 0) *scnt = 0;
    __syncthreads();
    u16 u = ((const u16*)p)[tid & 255];
    int e = (u >> 7) & 0xff;
    if (e != 0 && (e < 90 || e > 160)) atomicAdd(scnt, 1);
    __syncthreads();
    return *scnt > 64;
}

// ===================== mega: gating/normx (z<2) + 24 weight-mat transposes (z>=2) =====================
// Round-4 proven structure: 64-row x 128-col tile of ONE mat per block (two 64x64 subtiles),
// 8 outstanding float4 loads per thread, single uniform fp branch, single sniff.
__global__ void k_mega(const void* __restrict__ x, const void* __restrict__ wg,
                       const void* __restrict__ w1, const void* __restrict__ w3,
                       const void* __restrict__ w2, u16* __restrict__ wt,
                       u16* __restrict__ xb, void* __restrict__ out_base,
                       int* __restrict__ te, float* __restrict__ tw) {
    __shared__ int scnt;
    __shared__ __align__(16) u16 sT[2][64 * 68];   // two transposed 64x64 subtiles [c][r], stride 68
    int z = blockIdx.z, tid = threadIdx.x;

    if (z >= 2) {
        // ---- transpose plane: 12 z-planes x 256 blocks = 24 mats x (16 row-tiles x 8 col-tiles) ----
        int zz = z - 2;
        int mat = zz * 2 + (blockIdx.x >> 3);      // 2 mats per z-plane
        int which = mat >> 3, lm = mat & 7;
        const void* src0 = which == 0 ? w1 : (which == 1 ? w3 : w2);
        int fp = sniff_fp(src0, tid, &scnt);
        u16* dst = wt + (size_t)mat * 1048576;
        int rg = tid >> 4, cg = tid & 15;          // 16 row-groups x 16 col-groups of 4x4
        int r0 = blockIdx.y * 64, c0 = (blockIdx.x & 7) * 128;
        int rbase = r0 + rg * 4, cbase = c0 + cg * 4;

        u16 vA[4][4], vB[4][4];                    // subtile A: cols cbase.., B: cols cbase+64..
        if (fp) {
            const float* sp = (const float*)src0 + (size_t)lm * 1048576;
            float4 fA[4], fB[4];
            // issue all 8 loads before any use
#pragma unroll
            for (int i = 0; i < 4; i++) fA[i] = *(const float4*)(sp + (size_t)(rbase + i) * 1024 + cbase);
#pragma unroll
            for (int i = 0; i < 4; i++) fB[i] = *(const float4*)(sp + (size_t)(rbase + i) * 1024 + cbase + 64);
#pragma unroll
            for (int i = 0; i < 4; i++) {
                vA[i][0] = f2bf(fA[i].x); vA[i][1] = f2bf(fA[i].y);
                vA[i][2] = f2bf(fA[i].z); vA[i][3] = f2bf(fA[i].w);
                vB[i][0] = f2bf(fB[i].x); vB[i][1] = f2bf(fB[i].y);
                vB[i][2] = f2bf(fB[i].z); vB[i][3] = f2bf(fB[i].w);
            }
        } else {
            const u16* sp = (const u16*)src0 + (size_t)lm * 1048576;
            uint2 uA[4], uB[4];
#pragma unroll
            for (int i = 0; i < 4; i++) uA[i] = *(const uint2*)(sp + (size_t)(rbase + i) * 1024 + cbase);
#pragma unroll
            for (int i = 0; i < 4; i++) uB[i] = *(const uint2*)(sp + (size_t)(rbase + i) * 1024 + cbase + 64);
#pragma unroll
            for (int i = 0; i < 4; i++) { *(uint2*)&vA[i][0] = uA[i]; *(uint2*)&vB[i][0] = uB[i]; }
        }
        // register 4x4 transpose -> LDS [c][r]; 8B writes
#pragma unroll
        for (int j = 0; j < 4; j++) {
            uint2 wa, wb;
            wa.x = (uint32_t)vA[0][j] | ((uint32_t)vA[1][j] << 16);
            wa.y = (uint32_t)vA[2][j] | ((uint32_t)vA[3][j] << 16);
            wb.x = (uint32_t)vB[0][j] | ((uint32_t)vB[1][j] << 16);
            wb.y = (uint32_t)vB[2][j] | ((uint32_t)vB[3][j] << 16);
            *(uint2*)&sT[0][(cg * 4 + j) * 68 + rg * 4] = wa;
            *(uint2*)&sT[1][(cg * 4 + j) * 68 + rg * 4] = wb;
        }
        __syncthreads();
        // read back transposed rows: thread -> (local out-row cc, 16-elem segment seg)
        int cc = tid >> 2, seg = tid & 3;
#pragma unroll
        for (int b = 0; b < 2; b++) {
            const u16* spp = &sT[b][cc * 68 + seg * 16];
            uint2 q0 = *(const uint2*)(spp);
            uint2 q1 = *(const uint2*)(spp + 4);
            uint2 q2 = *(const uint2*)(spp + 8);
            uint2 q3 = *(const uint2*)(spp + 12);
            u16* dp = dst + (size_t)(c0 + b * 64 + cc) * 1024 + r0 + seg * 16;
            uint4 o0, o1;
            o0.x = q0.x; o0.y = q0.y; o0.z = q1.x; o0.w = q1.y;
            o1.x = q2.x; o1.y = q2.y; o1.z = q3.x; o1.w = q3.y;
            *(uint4*)dp = o0;
            *(uint4*)(dp + 8) = o1;
        }
    } else {
        // ---- gating plane: 512 blocks, 4 tokens each; also emits xb (bf16 x) ----
        // Vectorized: 4 floats/lane/iter, 4 iters.
        int fp = sniff_fp(x, tid, &scnt);
        int gi = z * 256 + blockIdx.y * 16 + blockIdx.x;
        int wave = tid >> 6, lane = tid & 63;
        int n = gi * 4 + wave;
        float acc[8];
#pragma unroll
        for (int e = 0; e < 8; e++) acc[e] = 0.f;
        if (fp) {
            const float* xp = (const float*)x + (size_t)n * DDIM;
            const float* wp = (const float*)wg;
#pragma unroll
            for (int it = 0; it < 4; ++it) {
                int d = it * 256 + lane * 4;
                float4 xv = *(const float4*)(xp + d);
                u16 pk[4] = { f2bf(xv.x), f2bf(xv.y), f2bf(xv.z), f2bf(xv.w) };
                *(uint2*)&xb[(size_t)n * DDIM + d] = *(const uint2*)pk;
#pragma unroll
                for (int e = 0; e < 8; e++) {
                    float4 w4 = *(const float4*)(wp + e * DDIM + d);
                    acc[e] += xv.x * w4.x + xv.y * w4.y + xv.z * w4.z + xv.w * w4.w;
                }
            }
        } else {
            const u16* xp = (const u16*)x + (size_t)n * DDIM;
            const u16* wp = (const u16*)wg;
#pragma unroll
            for (int it = 0; it < 4; ++it) {
                int d = it * 256 + lane * 4;
                uint2 raw = *(const uint2*)(xp + d);
                *(uint2*)&xb[(size_t)n * DDIM + d] = raw;
                const u16* rp = (const u16*)&raw;
                float x0 = bf2f(rp[0]), x1 = bf2f(rp[1]), x2 = bf2f(rp[2]), x3 = bf2f(rp[3]);
#pragma unroll
                for (int e = 0; e < 8; e++) {
                    uint2 wr = *(const uint2*)(wp + e * DDIM + d);
                    const u16* wq = (const u16*)&wr;
                    acc[e] += x0 * bf2f(wq[0]) + x1 * bf2f(wq[1]) + x2 * bf2f(wq[2]) + x3 * bf2f(wq[3]);
                }
            }
        }
#pragma unroll
        for (int e = 0; e < 8; e++) {
            for (int off = 32; off; off >>= 1) acc[e] += __shfl_xor(acc[e], off);
        }
        if (lane < 8) {
            if (fp) ((float*)out_base + (size_t)N_TOK * DDIM)[n * 8 + lane] = acc[lane];
            else    ((u16*)out_base + (size_t)N_TOK * DDIM)[n * 8 + lane] = f2bf(acc[lane]);
        }
        if (lane == 0) {
            int e0 = 0; float b0 = acc[0];
            for (int e = 1; e < 8; e++) if (acc[e] > b0) { b0 = acc[e]; e0 = e; }
            int e1 = -1; float b1 = -1e30f;
            for (int e = 0; e < 8; e++) if (e != e0 && acc[e] > b1) { b1 = acc[e]; e1 = e; }
            float m = fmaxf(b0, b1);
            float x0 = __expf(b0 - m), x1 = __expf(b1 - m);
            float sden = x0 + x1;
            te[n * 2] = e0; te[n * 2 + 1] = e1;
            tw[n * 2] = x0 / sden; tw[n * 2 + 1] = x1 / sden;
        }
    }
}

// ---------------- scheduling ----------------
__global__ void k_sched(const int* __restrict__ te, const float* __restrict__ tw,
                        int* __restrict__ pair_token, float* __restrict__ pair_weight,
                        int* __restrict__ ppos, int* __restrict__ sched) {
    __shared__ int cnt[8], cur[8];
    int t = threadIdx.x;
    if (t < 8) cnt[t] = 0;
    __syncthreads();
    for (int n = t; n < N_TOK; n += 256) {
        atomicAdd(&cnt[te[2 * n]], 1);
        atomicAdd(&cnt[te[2 * n + 1]], 1);
    }
    __syncthreads();
    if (t == 0) {
        int o = 0, mt = 0;
        for (int e = 0; e < 8; e++) {
            cur[e] = o;
            int c = cnt[e];
            for (int m0 = 0; m0 < c; m0 += 128) {
                sched[mt] = e;
                sched[MAXMT + mt] = o + m0;
                sched[2 * MAXMT + mt] = (c - m0 < 128) ? (c - m0) : 128;
                mt++;
            }
            o += c;
        }
        sched[3 * MAXMT] = mt;
        for (int i = mt; i < MAXMT; i++) { sched[i] = 0; sched[MAXMT + i] = 0; sched[2 * MAXMT + i] = 0; }
    }
    __syncthreads();
    for (int n = t; n < N_TOK; n += 256) {
#pragma unroll
        for (int s = 0; s < 2; s++) {
            int e = te[2 * n + s];
            int p = atomicAdd(&cur[e], 1);
            pair_token[p] = n;
            pair_weight[p] = tw[2 * n + s];
            ppos[2 * n + s] = p;
        }
    }
}

// ===================== fused SwiGLU GEMM: Abuf = silu(X@W1) * (X@W3) =====================
// Tile: 128 pairs x 128 f-cols (was 128x64), BK=64, single-buffered 48KB LDS.
// Mechanism: staging traffic is the limiter (L3-BW-bound re-reads of weight panels);
// doubling BN halves staged bytes per FLOP (320MB -> 160MB per iteration).
// 4 waves, each owns a 64m x 64n sub-tile; acc 4x4 fragments per matmul (~210 VGPR, no spill
// at launch_bounds(256,2)). Serial stage->sync->compute (dbuf proven neutral r1).
__launch_bounds__(256, 2)
__global__ void k_gemm13(const u16* __restrict__ xb, const u16* __restrict__ w1t,
                         const u16* __restrict__ w3t, const int* __restrict__ pair_token,
                         const int* __restrict__ sched, u16* __restrict__ Abuf) {
    __shared__ __align__(16) u16 smem[24576];     // 48 KB: sA 128x64 | sB1 128x64 | sB3 128x64
    u16* sA  = smem;
    u16* sB1 = smem + 8192;
    u16* sB3 = smem + 16384;

    int bn = blockIdx.x;          // 8 tiles of 128 f-cols
    int bm = blockIdx.y;
    int total = sched[3 * MAXMT];
    if (bm >= total) return;
    int e = sched[bm];
    int row0 = sched[MAXMT + bm];
    int rowsv = sched[2 * MAXMT + bm];

    int tid = threadIdx.x;
    int wave = tid >> 6, lane = tid & 63;
    int wm = wave & 1, wn = wave >> 1;            // wave: 64m x 64n
    int quad = lane >> 4, l15 = lane & 15;
    int lsub = lane >> 3, slot = lane & 7;

    const u16* gA[4]; int aoff[4];
    const u16* gB1[4]; const u16* gB3[4]; int boff[4];
#pragma unroll
    for (int c = 0; c < 4; c++) {
        int row = c * 32 + wave * 8 + lsub;       // 0..127
        int cr = row < rowsv ? row : 0;
        int tok = pair_token[row0 + cr];
        int gch = slot ^ (row & 7);
        gA[c] = xb + (size_t)tok * DDIM + gch * 8;
        aoff[c] = c * 2048 + wave * 512;
        int fcol = bn * 128 + row;                // 0..1023
        gB1[c] = w1t + ((size_t)e * 1024 + fcol) * 1024 + gch * 8;
        gB3[c] = w3t + ((size_t)e * 1024 + fcol) * 1024 + gch * 8;
        boff[c] = c * 2048 + wave * 512;
    }

    f32x4 acc_h[4][4], acc_u[4][4];
#pragma unroll
    for (int i = 0; i < 4; i++)
#pragma unroll
        for (int j = 0; j < 4; j++) { acc_h[i][j] = (f32x4)0.f; acc_u[i][j] = (f32x4)0.f; }

    for (int kt = 0; kt < 16; ++kt) {
        int k0 = kt * 64;
        __syncthreads();              // previous compute done before overwrite
#pragma unroll
        for (int c = 0; c < 4; c++) {
            async_copy16(gA[c] + k0, sA + aoff[c]);
            async_copy16(gB1[c] + k0, sB1 + boff[c]);
            async_copy16(gB3[c] + k0, sB3 + boff[c]);
        }
        __syncthreads();              // drain stage
#pragma unroll
        for (int kk = 0; kk < 2; ++kk) {
            bf16x8 a[4], b1[4], b3[4];
#pragma unroll
            for (int i = 0; i < 4; i++) {
                int m = wm * 64 + i * 16 + l15;
                int s = (kk * 4 + quad) ^ (m & 7);
                a[i] = *(const bf16x8*)&sA[m * 64 + s * 8];
            }
#pragma unroll
            for (int j = 0; j < 4; j++) {
                int nn = wn * 64 + j * 16 + l15;
                int s = (kk * 4 + quad) ^ (nn & 7);
                b1[j] = *(const bf16x8*)&sB1[nn * 64 + s * 8];
                b3[j] = *(const bf16x8*)&sB3[nn * 64 + s * 8];
            }
#pragma unroll
            for (int i = 0; i < 4; i++)
#pragma unroll
                for (int j = 0; j < 4; j++) {
                    acc_h[i][j] = __builtin_amdgcn_mfma_f32_16x16x32_bf16(a[i], b1[j], acc_h[i][j], 0, 0, 0);
                    acc_u[i][j] = __builtin_amdgcn_mfma_f32_16x16x32_bf16(a[i], b3[j], acc_u[i][j], 0, 0, 0);
                }
        }
    }
    // epilogue: silu(h)*u -> LDS (stride 136) -> vectorized global stores
    __syncthreads();
#pragma unroll
    for (int i = 0; i < 4; i++)
#pragma unroll
        for (int j = 0; j < 4; j++)
#pragma unroll
            for (int r = 0; r < 4; r++) {
                int row = wm * 64 + i * 16 + quad * 4 + r;
                int col = wn * 64 + j * 16 + l15;
                float h = acc_h[i][j][r], u = acc_u[i][j][r];
                smem[row * 136 + col] = f2bf(h * u / (1.0f + __expf(-h)));
            }
    __syncthreads();
    int rt = tid >> 1, half = tid & 1;
    if (rt < rowsv) {
        u16* dp = Abuf + (size_t)(row0 + rt) * FDIM + bn * 128 + half * 64;
        const u16* sp = &smem[rt * 136 + half * 64];
#pragma unroll
        for (int q = 0; q < 8; q++)
            *(uint4*)(dp + q * 8) = *(const uint4*)(sp + q * 8);
    }
}

// ===================== GEMM2: Ybuf = Abuf @ W2t =====================
// Same BN=128 widening: 128x128 tile, single-buffered 32KB staging (34KB incl. epilogue).
__launch_bounds__(256, 3)
__global__ void k_gemm2(const u16* __restrict__ Abuf, const u16* __restrict__ w2t,
                        const int* __restrict__ sched, u16* __restrict__ Ybuf) {
    __shared__ __align__(16) u16 smem[17408];     // 34 KB: staging sA|sB (32KB), epilogue 128x136
    u16* sA = smem;
    u16* sB = smem + 8192;

    int bn = blockIdx.x;          // 8 tiles of 128 d-cols
    int bm = blockIdx.y;
    int total = sched[3 * MAXMT];
    if (bm >= total) return;
    int e = sched[bm];
    int row0 = sched[MAXMT + bm];
    int rowsv = sched[2 * MAXMT + bm];

    int tid = threadIdx.x;
    int wave = tid >> 6, lane = tid & 63;
    int wm = wave & 1, wn = wave >> 1;
    int quad = lane >> 4, l15 = lane & 15;
    int lsub = lane >> 3, slot = lane & 7;

    const u16* gA[4]; int aoff[4];
    const u16* gB[4]; int boff[4];
#pragma unroll
    for (int c = 0; c < 4; c++) {
        int row = c * 32 + wave * 8 + lsub;       // 0..127
        int cr = row < rowsv ? row : 0;
        int gch = slot ^ (row & 7);
        gA[c] = Abuf + (size_t)(row0 + cr) * FDIM + gch * 8;
        aoff[c] = c * 2048 + wave * 512;
        int dcol = bn * 128 + row;
        gB[c] = w2t + ((size_t)e * 1024 + dcol) * 1024 + gch * 8;
        boff[c] = c * 2048 + wave * 512;
    }

    f32x4 acc[4][4];
#pragma unroll
    for (int i = 0; i < 4; i++)
#pragma unroll
        for (int j = 0; j < 4; j++) acc[i][j] = (f32x4)0.f;

    for (int kt = 0; kt < 16; ++kt) {
        int k0 = kt * 64;
        __syncthreads();
#pragma unroll
        for (int c = 0; c < 4; c++) {
            async_copy16(gA[c] + k0, sA + aoff[c]);
            async_copy16(gB[c] + k0, sB + boff[c]);
        }
        __syncthreads();
#pragma unroll
        for (int kk = 0; kk < 2; ++kk) {
            bf16x8 a[4], b[4];
#pragma unroll
            for (int i = 0; i < 4; i++) {
                int m = wm * 64 + i * 16 + l15;
                int s = (kk * 4 + quad) ^ (m & 7);
                a[i] = *(const bf16x8*)&sA[m * 64 + s * 8];
            }
#pragma unroll
            for (int j = 0; j < 4; j++) {
                int nn = wn * 64 + j * 16 + l15;
                int s = (kk * 4 + quad) ^ (nn & 7);
                b[j] = *(const bf16x8*)&sB[nn * 64 + s * 8];
            }
#pragma unroll
            for (int i = 0; i < 4; i++)
#pragma unroll
                for (int j = 0; j < 4; j++)
                    acc[i][j] = __builtin_amdgcn_mfma_f32_16x16x32_bf16(a[i], b[j], acc[i][j], 0, 0, 0);
        }
    }
    __syncthreads();
#pragma unroll
    for (int i = 0; i < 4; i++)
#pragma unroll
        for (int j = 0; j < 4; j++)
#pragma unroll
            for (int r = 0; r < 4; r++) {
                int row = wm * 64 + i * 16 + quad * 4 + r;
                int col = wn * 64 + j * 16 + l15;
                smem[row * 136 + col] = f2bf(acc[i][j][r]);
            }
    __syncthreads();
    int rt = tid >> 1, half = tid & 1;
    if (rt < rowsv) {
        u16* dp = Ybuf + (size_t)(row0 + rt) * DDIM + bn * 128 + half * 64;
        const u16* sp = &smem[rt * 136 + half * 64];
#pragma unroll
        for (int q = 0; q < 8; q++)
            *(uint4*)(dp + q * 8) = *(const uint4*)(sp + q * 8);
    }
}

// ---------------- combine: out[n] = w0*Y[p0] + w1*Y[p1] ----------------
__global__ void k_combine(const u16* __restrict__ Y, const int* __restrict__ ppos,
                          const float* __restrict__ pwt, const void* __restrict__ x,
                          void* __restrict__ out) {
    __shared__ int scnt;
    int n = blockIdx.x, t = threadIdx.x;
    int fp = sniff_fp(x, t, &scnt);
    int p0 = ppos[2 * n], p1 = ppos[2 * n + 1];
    float w0 = pwt[p0], w1 = pwt[p1];
    uint2 a = *(const uint2*)(Y + (size_t)p0 * 1024 + t * 4);
    uint2 b = *(const uint2*)(Y + (size_t)p1 * 1024 + t * 4);
    const u16* ap = (const u16*)&a;
    const u16* bp = (const u16*)&b;
    float r[4];
#pragma unroll
    for (int j = 0; j < 4; j++) r[j] = w0 * bf2f(ap[j]) + w1 * bf2f(bp[j]);
    if (fp) {
        float4 o = { r[0], r[1], r[2], r[3] };
        *(float4*)((float*)out + (size_t)n * 1024 + t * 4) = o;
    } else {
        u16 o[4] = { f2bf(r[0]), f2bf(r[1]), f2bf(r[2]), f2bf(r[3]) };
        *(uint2*)((u16*)out + (size_t)n * 1024 + t * 4) = *(const uint2*)o;
    }
}

extern "C" void kernel_launch(void* const* d_in, const int* in_sizes, int n_in,
                              void* d_out, int out_size, void* d_ws, size_t ws_size,
                              hipStream_t stream) {
    const void* x  = d_in[0];
    const void* wg = d_in[1];
    const void* w1 = d_in[2];
    const void* w3 = d_in[3];
    const void* w2 = d_in[4];

    u16* wt   = (u16*)d_ws;                  // 48 MB: w1t(8 mats) | w3t | w2t
    u16* w1t  = wt;
    u16* w3t  = wt + (size_t)8 * 1048576;
    u16* w2t  = wt + (size_t)16 * 1048576;
    u16* Abuf = wt + (size_t)24 * 1048576;   // 8 MB
    u16* Ybuf = Abuf + (size_t)4096 * 1024;  // 8 MB
    u16* xb   = Ybuf + (size_t)4096 * 1024;  // 4 MB
    int*   te   = (int*)(xb + (size_t)N_TOK * DDIM);
    float* tw   = (float*)(te + 2 * N_TOK);
    int*   ptok = (int*)(tw + 2 * N_TOK);
    float* pwt  = (float*)(ptok + 2 * N_TOK);
    int*   ppos = (int*)(pwt + 2 * N_TOK);
    int*   sched = ppos + 2 * N_TOK;

    k_mega<<<dim3(16, 16, 14), 256, 0, stream>>>(x, wg, w1, w3, w2, wt, xb, d_out, te, tw);
    k_sched<<<1, 256, 0, stream>>>(te, tw, ptok, pwt, ppos, sched);
    k_gemm13<<<dim3(8, MAXMT), 256, 0, stream>>>(xb, w1t, w3t, ptok, sched, Abuf);
    k_gemm2<<<dim3(8, MAXMT), 256, 0, stream>>>(Abuf, w2t, sched, Ybuf);
    k_combine<<<2048, 256, 0, stream>>>(Ybuf, ppos, pwt, x, d_out);
}

// Round 10
// 198.689 us; speedup vs baseline: 1.0497x; 1.0497x over previous
//
#include <hip/hip_runtime.h>
#include <stdint.h>

typedef unsigned short u16;
typedef __attribute__((ext_vector_type(8))) __bf16 bf16x8;
typedef __attribute__((ext_vector_type(4))) float f32x4;

#define MAXMT 40
#define N_TOK 2048
#define DDIM 1024
#define FDIM 1024

#define DEV static __device__ __forceinline__

DEV float bf2f(u16 u) {
    union { uint32_t i; float f; } v;
    v.i = ((uint32_t)u) << 16;
    return v.f;
}
DEV u16 f2bf(float f) {
    union { float f; uint32_t i; } v;
    v.f = f;
    uint32_t x = v.i;
    return (u16)((x + 0x7fffu + ((x >> 16) & 1u)) >> 16);  // RNE
}

// async global->LDS, 16B per lane; lds base wave-uniform, HW writes lane i at base+16*i
DEV void async_copy16(const u16* gsrc, u16* ldst) {
    __builtin_amdgcn_global_load_lds(
        (const __attribute__((address_space(1))) void*)(uintptr_t)gsrc,
        (__attribute__((address_space(3))) void*)(uint32_t)(uintptr_t)ldst,
        16, 0, 0);
}

// per-block dtype sniff: sample first 256 u16 of tensor; fp32-reinterpreted data has
// ~36% wild exponent fields, bf16 ~0%. Returns 1 => fp32.
DEV int sniff_fp(const void* p, int tid, int* scnt) {
    if (tid == 0) *scnt = 0;
    __syncthreads();
    u16 u = ((const u16*)p)[tid & 255];
    int e = (u >> 7) & 0xff;
    if (e != 0 && (e < 90 || e > 160)) atomicAdd(scnt, 1);
    __syncthreads();
    return *scnt > 64;
}

// ===================== mega: gating/normx (z<2) + 24 weight-mat transposes (z>=2) =====================
// Round-4 proven structure: 64-row x 128-col tile of ONE mat per block (two 64x64 subtiles),
// 8 outstanding float4 loads per thread, single uniform fp branch, single sniff.
__global__ void k_mega(const void* __restrict__ x, const void* __restrict__ wg,
                       const void* __restrict__ w1, const void* __restrict__ w3,
                       const void* __restrict__ w2, u16* __restrict__ wt,
                       u16* __restrict__ xb, void* __restrict__ out_base,
                       int* __restrict__ te, float* __restrict__ tw) {
    __shared__ int scnt;
    __shared__ __align__(16) u16 sT[2][64 * 68];   // two transposed 64x64 subtiles [c][r], stride 68
    int z = blockIdx.z, tid = threadIdx.x;

    if (z >= 2) {
        // ---- transpose plane: 12 z-planes x 256 blocks = 24 mats x (16 row-tiles x 8 col-tiles) ----
        int zz = z - 2;
        int mat = zz * 2 + (blockIdx.x >> 3);      // 2 mats per z-plane
        int which = mat >> 3, lm = mat & 7;
        const void* src0 = which == 0 ? w1 : (which == 1 ? w3 : w2);
        int fp = sniff_fp(src0, tid, &scnt);
        u16* dst = wt + (size_t)mat * 1048576;
        int rg = tid >> 4, cg = tid & 15;          // 16 row-groups x 16 col-groups of 4x4
        int r0 = blockIdx.y * 64, c0 = (blockIdx.x & 7) * 128;
        int rbase = r0 + rg * 4, cbase = c0 + cg * 4;

        u16 vA[4][4], vB[4][4];                    // subtile A: cols cbase.., B: cols cbase+64..
        if (fp) {
            const float* sp = (const float*)src0 + (size_t)lm * 1048576;
            float4 fA[4], fB[4];
            // issue all 8 loads before any use
#pragma unroll
            for (int i = 0; i < 4; i++) fA[i] = *(const float4*)(sp + (size_t)(rbase + i) * 1024 + cbase);
#pragma unroll
            for (int i = 0; i < 4; i++) fB[i] = *(const float4*)(sp + (size_t)(rbase + i) * 1024 + cbase + 64);
#pragma unroll
            for (int i = 0; i < 4; i++) {
                vA[i][0] = f2bf(fA[i].x); vA[i][1] = f2bf(fA[i].y);
                vA[i][2] = f2bf(fA[i].z); vA[i][3] = f2bf(fA[i].w);
                vB[i][0] = f2bf(fB[i].x); vB[i][1] = f2bf(fB[i].y);
                vB[i][2] = f2bf(fB[i].z); vB[i][3] = f2bf(fB[i].w);
            }
        } else {
            const u16* sp = (const u16*)src0 + (size_t)lm * 1048576;
            uint2 uA[4], uB[4];
#pragma unroll
            for (int i = 0; i < 4; i++) uA[i] = *(const uint2*)(sp + (size_t)(rbase + i) * 1024 + cbase);
#pragma unroll
            for (int i = 0; i < 4; i++) uB[i] = *(const uint2*)(sp + (size_t)(rbase + i) * 1024 + cbase + 64);
#pragma unroll
            for (int i = 0; i < 4; i++) { *(uint2*)&vA[i][0] = uA[i]; *(uint2*)&vB[i][0] = uB[i]; }
        }
        // register 4x4 transpose -> LDS [c][r]; 8B writes
#pragma unroll
        for (int j = 0; j < 4; j++) {
            uint2 wa, wb;
            wa.x = (uint32_t)vA[0][j] | ((uint32_t)vA[1][j] << 16);
            wa.y = (uint32_t)vA[2][j] | ((uint32_t)vA[3][j] << 16);
            wb.x = (uint32_t)vB[0][j] | ((uint32_t)vB[1][j] << 16);
            wb.y = (uint32_t)vB[2][j] | ((uint32_t)vB[3][j] << 16);
            *(uint2*)&sT[0][(cg * 4 + j) * 68 + rg * 4] = wa;
            *(uint2*)&sT[1][(cg * 4 + j) * 68 + rg * 4] = wb;
        }
        __syncthreads();
        // read back transposed rows: thread -> (local out-row cc, 16-elem segment seg)
        int cc = tid >> 2, seg = tid & 3;
#pragma unroll
        for (int b = 0; b < 2; b++) {
            const u16* spp = &sT[b][cc * 68 + seg * 16];
            uint2 q0 = *(const uint2*)(spp);
            uint2 q1 = *(const uint2*)(spp + 4);
            uint2 q2 = *(const uint2*)(spp + 8);
            uint2 q3 = *(const uint2*)(spp + 12);
            u16* dp = dst + (size_t)(c0 + b * 64 + cc) * 1024 + r0 + seg * 16;
            uint4 o0, o1;
            o0.x = q0.x; o0.y = q0.y; o0.z = q1.x; o0.w = q1.y;
            o1.x = q2.x; o1.y = q2.y; o1.z = q3.x; o1.w = q3.y;
            *(uint4*)dp = o0;
            *(uint4*)(dp + 8) = o1;
        }
    } else {
        // ---- gating plane: 512 blocks, 4 tokens each; also emits xb (bf16 x) ----
        // Vectorized: 4 floats/lane/iter, 4 iters.
        int fp = sniff_fp(x, tid, &scnt);
        int gi = z * 256 + blockIdx.y * 16 + blockIdx.x;
        int wave = tid >> 6, lane = tid & 63;
        int n = gi * 4 + wave;
        float acc[8];
#pragma unroll
        for (int e = 0; e < 8; e++) acc[e] = 0.f;
        if (fp) {
            const float* xp = (const float*)x + (size_t)n * DDIM;
            const float* wp = (const float*)wg;
#pragma unroll
            for (int it = 0; it < 4; ++it) {
                int d = it * 256 + lane * 4;
                float4 xv = *(const float4*)(xp + d);
                u16 pk[4] = { f2bf(xv.x), f2bf(xv.y), f2bf(xv.z), f2bf(xv.w) };
                *(uint2*)&xb[(size_t)n * DDIM + d] = *(const uint2*)pk;
#pragma unroll
                for (int e = 0; e < 8; e++) {
                    float4 w4 = *(const float4*)(wp + e * DDIM + d);
                    acc[e] += xv.x * w4.x + xv.y * w4.y + xv.z * w4.z + xv.w * w4.w;
                }
            }
        } else {
            const u16* xp = (const u16*)x + (size_t)n * DDIM;
            const u16* wp = (const u16*)wg;
#pragma unroll
            for (int it = 0; it < 4; ++it) {
                int d = it * 256 + lane * 4;
                uint2 raw = *(const uint2*)(xp + d);
                *(uint2*)&xb[(size_t)n * DDIM + d] = raw;
                const u16* rp = (const u16*)&raw;
                float x0 = bf2f(rp[0]), x1 = bf2f(rp[1]), x2 = bf2f(rp[2]), x3 = bf2f(rp[3]);
#pragma unroll
                for (int e = 0; e < 8; e++) {
                    uint2 wr = *(const uint2*)(wp + e * DDIM + d);
                    const u16* wq = (const u16*)&wr;
                    acc[e] += x0 * bf2f(wq[0]) + x1 * bf2f(wq[1]) + x2 * bf2f(wq[2]) + x3 * bf2f(wq[3]);
                }
            }
        }
#pragma unroll
        for (int e = 0; e < 8; e++) {
            for (int off = 32; off; off >>= 1) acc[e] += __shfl_xor(acc[e], off);
        }
        if (lane < 8) {
            if (fp) ((float*)out_base + (size_t)N_TOK * DDIM)[n * 8 + lane] = acc[lane];
            else    ((u16*)out_base + (size_t)N_TOK * DDIM)[n * 8 + lane] = f2bf(acc[lane]);
        }
        if (lane == 0) {
            int e0 = 0; float b0 = acc[0];
            for (int e = 1; e < 8; e++) if (acc[e] > b0) { b0 = acc[e]; e0 = e; }
            int e1 = -1; float b1 = -1e30f;
            for (int e = 0; e < 8; e++) if (e != e0 && acc[e] > b1) { b1 = acc[e]; e1 = e; }
            float m = fmaxf(b0, b1);
            float x0 = __expf(b0 - m), x1 = __expf(b1 - m);
            float sden = x0 + x1;
            te[n * 2] = e0; te[n * 2 + 1] = e1;
            tw[n * 2] = x0 / sden; tw[n * 2 + 1] = x1 / sden;
        }
    }
}

// ---------------- scheduling (1024 threads: 4x fewer latency-bound global-load iters) ----------------
__global__ void k_sched(const int* __restrict__ te, const float* __restrict__ tw,
                        int* __restrict__ pair_token, float* __restrict__ pair_weight,
                        int* __restrict__ ppos, int* __restrict__ sched) {
    __shared__ int cnt[8], cur[8];
    int t = threadIdx.x;
    if (t < 8) cnt[t] = 0;
    __syncthreads();
    for (int n = t; n < N_TOK; n += 1024) {
        atomicAdd(&cnt[te[2 * n]], 1);
        atomicAdd(&cnt[te[2 * n + 1]], 1);
    }
    __syncthreads();
    if (t == 0) {
        int o = 0, mt = 0;
        for (int e = 0; e < 8; e++) {
            cur[e] = o;
            int c = cnt[e];
            for (int m0 = 0; m0 < c; m0 += 128) {
                sched[mt] = e;
                sched[MAXMT + mt] = o + m0;
                sched[2 * MAXMT + mt] = (c - m0 < 128) ? (c - m0) : 128;
                mt++;
            }
            o += c;
        }
        sched[3 * MAXMT] = mt;
        for (int i = mt; i < MAXMT; i++) { sched[i] = 0; sched[MAXMT + i] = 0; sched[2 * MAXMT + i] = 0; }
    }
    __syncthreads();
    for (int n = t; n < N_TOK; n += 1024) {
#pragma unroll
        for (int s = 0; s < 2; s++) {
            int e = te[2 * n + s];
            int p = atomicAdd(&cur[e], 1);
            pair_token[p] = n;
            pair_weight[p] = tw[2 * n + s];
            ppos[2 * n + s] = p;
        }
    }
}

// ===================== fused SwiGLU GEMM: Abuf = silu(X@W1) * (X@W3) =====================
// Tile: 128 pairs x 64 f-cols, BK=64. Double-buffered LDS (2x32KB): stage(t+1) issued
// before compute(t); one __syncthreads per K-tile.
__launch_bounds__(256, 2)
__global__ void k_gemm13(const u16* __restrict__ xb, const u16* __restrict__ w1t,
                         const u16* __restrict__ w3t, const int* __restrict__ pair_token,
                         const int* __restrict__ sched, u16* __restrict__ Abuf) {
    __shared__ __align__(16) u16 smem[32768];     // 64 KB = 2 buffers x (sA 16K | sB1 8K | sB3 8K)

    int bn = blockIdx.x;          // 16 tiles of 64 cols
    int bm = blockIdx.y;
    int total = sched[3 * MAXMT];
    if (bm >= total) return;
    int e = sched[bm];
    int row0 = sched[MAXMT + bm];
    int rowsv = sched[2 * MAXMT + bm];

    int tid = threadIdx.x;
    int wave = tid >> 6, lane = tid & 63;
    int wm = wave & 1, wn = wave >> 1;            // wave: 64m x 32n
    int quad = lane >> 4, l15 = lane & 15;
    int lsub = lane >> 3, slot = lane & 7;

    const u16* gA[4]; int aoff[4];
#pragma unroll
    for (int c = 0; c < 4; c++) {
        int row = c * 32 + wave * 8 + lsub;       // 0..127
        int cr = row < rowsv ? row : 0;
        int tok = pair_token[row0 + cr];
        int gch = slot ^ (row & 7);
        gA[c] = xb + (size_t)tok * DDIM + gch * 8;
        aoff[c] = c * 2048 + wave * 512;
    }
    const u16* gB1[2]; const u16* gB3[2]; int b1off[2], b3off[2];
#pragma unroll
    for (int c = 0; c < 2; c++) {
        int row = c * 32 + wave * 8 + lsub;       // 0..63
        int gch = slot ^ (row & 7);
        int fcol = bn * 64 + row;
        gB1[c] = w1t + ((size_t)e * 1024 + fcol) * 1024 + gch * 8;
        gB3[c] = w3t + ((size_t)e * 1024 + fcol) * 1024 + gch * 8;
        b1off[c] = 8192 + c * 2048 + wave * 512;
        b3off[c] = 12288 + c * 2048 + wave * 512;
    }

    f32x4 acc_h[4][2], acc_u[4][2];
#pragma unroll
    for (int i = 0; i < 4; i++)
#pragma unroll
        for (int j = 0; j < 2; j++) { acc_h[i][j] = (f32x4)0.f; acc_u[i][j] = (f32x4)0.f; }

    // prologue: stage tile 0 into buffer 0
#pragma unroll
    for (int c = 0; c < 4; c++) async_copy16(gA[c], smem + aoff[c]);
#pragma unroll
    for (int c = 0; c < 2; c++) {
        async_copy16(gB1[c], smem + b1off[c]);
        async_copy16(gB3[c], smem + b3off[c]);
    }

    for (int kt = 0; kt < 16; ++kt) {
        int cur = kt & 1;
        u16* sbuf = smem + cur * 16384;
        __syncthreads();              // drains stage(kt); orders reads(t-1) vs stage(t+1)
        if (kt < 15) {
            int k1 = (kt + 1) * 64;
            u16* nbuf = smem + (cur ^ 1) * 16384;
#pragma unroll
            for (int c = 0; c < 4; c++) async_copy16(gA[c] + k1, nbuf + aoff[c]);
#pragma unroll
            for (int c = 0; c < 2; c++) {
                async_copy16(gB1[c] + k1, nbuf + b1off[c]);
                async_copy16(gB3[c] + k1, nbuf + b3off[c]);
            }
        }
        const u16* sA_  = sbuf;
        const u16* sB1_ = sbuf + 8192;
        const u16* sB3_ = sbuf + 12288;
#pragma unroll
        for (int kk = 0; kk < 2; ++kk) {
            bf16x8 a[4], b1[2], b3[2];
#pragma unroll
            for (int i = 0; i < 4; i++) {
                int m = wm * 64 + i * 16 + l15;
                int s = (kk * 4 + quad) ^ (m & 7);
                a[i] = *(const bf16x8*)&sA_[m * 64 + s * 8];
            }
#pragma unroll
            for (int j = 0; j < 2; j++) {
                int nn = wn * 32 + j * 16 + l15;
                int s = (kk * 4 + quad) ^ (nn & 7);
                b1[j] = *(const bf16x8*)&sB1_[nn * 64 + s * 8];
                b3[j] = *(const bf16x8*)&sB3_[nn * 64 + s * 8];
            }
#pragma unroll
            for (int i = 0; i < 4; i++)
#pragma unroll
                for (int j = 0; j < 2; j++) {
                    acc_h[i][j] = __builtin_amdgcn_mfma_f32_16x16x32_bf16(a[i], b1[j], acc_h[i][j], 0, 0, 0);
                    acc_u[i][j] = __builtin_amdgcn_mfma_f32_16x16x32_bf16(a[i], b3[j], acc_u[i][j], 0, 0, 0);
                }
        }
    }
    // epilogue: silu(h)*u -> LDS (stride 72) -> vectorized global stores
    __syncthreads();
#pragma unroll
    for (int i = 0; i < 4; i++)
#pragma unroll
        for (int j = 0; j < 2; j++)
#pragma unroll
            for (int r = 0; r < 4; r++) {
                int row = wm * 64 + i * 16 + quad * 4 + r;
                int col = wn * 32 + j * 16 + l15;
                float h = acc_h[i][j][r], u = acc_u[i][j][r];
                smem[row * 72 + col] = f2bf(h * u / (1.0f + __expf(-h)));
            }
    __syncthreads();
    int rt = tid >> 1, half = tid & 1;
    if (rt < rowsv) {
        u16* dp = Abuf + (size_t)(row0 + rt) * FDIM + bn * 64 + half * 32;
        const u16* sp = &smem[rt * 72 + half * 32];
#pragma unroll
        for (int q = 0; q < 4; q++)
            *(uint4*)(dp + q * 8) = *(const uint4*)(sp + q * 8);
    }
}

// ===================== GEMM2: Ybuf = Abuf @ W2t =====================
__launch_bounds__(256, 3)
__global__ void k_gemm2(const u16* __restrict__ Abuf, const u16* __restrict__ w2t,
                        const int* __restrict__ sched, u16* __restrict__ Ybuf) {
    __shared__ __align__(16) u16 smem[24576];     // 48 KB = 2 buffers x (sA 16K | sB 8K)

    int bn = blockIdx.x;
    int bm = blockIdx.y;
    int total = sched[3 * MAXMT];
    if (bm >= total) return;
    int e = sched[bm];
    int row0 = sched[MAXMT + bm];
    int rowsv = sched[2 * MAXMT + bm];

    int tid = threadIdx.x;
    int wave = tid >> 6, lane = tid & 63;
    int wm = wave & 1, wn = wave >> 1;
    int quad = lane >> 4, l15 = lane & 15;
    int lsub = lane >> 3, slot = lane & 7;

    const u16* gA[4]; int aoff[4];
#pragma unroll
    for (int c = 0; c < 4; c++) {
        int row = c * 32 + wave * 8 + lsub;
        int cr = row < rowsv ? row : 0;
        int gch = slot ^ (row & 7);
        gA[c] = Abuf + (size_t)(row0 + cr) * FDIM + gch * 8;
        aoff[c] = c * 2048 + wave * 512;
    }
    const u16* gB[2]; int boff[2];
#pragma unroll
    for (int c = 0; c < 2; c++) {
        int row = c * 32 + wave * 8 + lsub;
        int gch = slot ^ (row & 7);
        int dcol = bn * 64 + row;
        gB[c] = w2t + ((size_t)e * 1024 + dcol) * 1024 + gch * 8;
        boff[c] = 8192 + c * 2048 + wave * 512;
    }

    f32x4 acc[4][2];
#pragma unroll
    for (int i = 0; i < 4; i++)
#pragma unroll
        for (int j = 0; j < 2; j++) acc[i][j] = (f32x4)0.f;

    // prologue: stage tile 0 into buffer 0
#pragma unroll
    for (int c = 0; c < 4; c++) async_copy16(gA[c], smem + aoff[c]);
#pragma unroll
    for (int c = 0; c < 2; c++) async_copy16(gB[c], smem + boff[c]);

    for (int kt = 0; kt < 16; ++kt) {
        int cur = kt & 1;
        u16* sbuf = smem + cur * 12288;
        __syncthreads();
        if (kt < 15) {
            int k1 = (kt + 1) * 64;
            u16* nbuf = smem + (cur ^ 1) * 12288;
#pragma unroll
            for (int c = 0; c < 4; c++) async_copy16(gA[c] + k1, nbuf + aoff[c]);
#pragma unroll
            for (int c = 0; c < 2; c++) async_copy16(gB[c] + k1, nbuf + boff[c]);
        }
        const u16* sA_ = sbuf;
        const u16* sB_ = sbuf + 8192;
#pragma unroll
        for (int kk = 0; kk < 2; ++kk) {
            bf16x8 a[4], b[2];
#pragma unroll
            for (int i = 0; i < 4; i++) {
                int m = wm * 64 + i * 16 + l15;
                int s = (kk * 4 + quad) ^ (m & 7);
                a[i] = *(const bf16x8*)&sA_[m * 64 + s * 8];
            }
#pragma unroll
            for (int j = 0; j < 2; j++) {
                int nn = wn * 32 + j * 16 + l15;
                int s = (kk * 4 + quad) ^ (nn & 7);
                b[j] = *(const bf16x8*)&sB_[nn * 64 + s * 8];
            }
#pragma unroll
            for (int i = 0; i < 4; i++)
#pragma unroll
                for (int j = 0; j < 2; j++)
                    acc[i][j] = __builtin_amdgcn_mfma_f32_16x16x32_bf16(a[i], b[j], acc[i][j], 0, 0, 0);
        }
    }
    __syncthreads();
#pragma unroll
    for (int i = 0; i < 4; i++)
#pragma unroll
        for (int j = 0; j < 2; j++)
#pragma unroll
            for (int r = 0; r < 4; r++) {
                int row = wm * 64 + i * 16 + quad * 4 + r;
                int col = wn * 32 + j * 16 + l15;
                smem[row * 72 + col] = f2bf(acc[i][j][r]);
            }
    __syncthreads();
    int rt = tid >> 1, half = tid & 1;
    if (rt < rowsv) {
        u16* dp = Ybuf + (size_t)(row0 + rt) * DDIM + bn * 64 + half * 32;
        const u16* sp = &smem[rt * 72 + half * 32];
#pragma unroll
        for (int q = 0; q < 4; q++)
            *(uint4*)(dp + q * 8) = *(const uint4*)(sp + q * 8);
    }
}

// ---------------- combine: out[n] = w0*Y[p0] + w1*Y[p1] ----------------
__global__ void k_combine(const u16* __restrict__ Y, const int* __restrict__ ppos,
                          const float* __restrict__ pwt, const void* __restrict__ x,
                          void* __restrict__ out) {
    __shared__ int scnt;
    int n = blockIdx.x, t = threadIdx.x;
    int fp = sniff_fp(x, t, &scnt);
    int p0 = ppos[2 * n], p1 = ppos[2 * n + 1];
    float w0 = pwt[p0], w1 = pwt[p1];
    uint2 a = *(const uint2*)(Y + (size_t)p0 * 1024 + t * 4);
    uint2 b = *(const uint2*)(Y + (size_t)p1 * 1024 + t * 4);
    const u16* ap = (const u16*)&a;
    const u16* bp = (const u16*)&b;
    float r[4];
#pragma unroll
    for (int j = 0; j < 4; j++) r[j] = w0 * bf2f(ap[j]) + w1 * bf2f(bp[j]);
    if (fp) {
        float4 o = { r[0], r[1], r[2], r[3] };
        *(float4*)((float*)out + (size_t)n * 1024 + t * 4) = o;
    } else {
        u16 o[4] = { f2bf(r[0]), f2bf(r[1]), f2bf(r[2]), f2bf(r[3]) };
        *(uint2*)((u16*)out + (size_t)n * 1024 + t * 4) = *(const uint2*)o;
    }
}

extern "C" void kernel_launch(void* const* d_in, const int* in_sizes, int n_in,
                              void* d_out, int out_size, void* d_ws, size_t ws_size,
                              hipStream_t stream) {
    const void* x  = d_in[0];
    const void* wg = d_in[1];
    const void* w1 = d_in[2];
    const void* w3 = d_in[3];
    const void* w2 = d_in[4];

    u16* wt   = (u16*)d_ws;                  // 48 MB: w1t(8 mats) | w3t | w2t
    u16* w1t  = wt;
    u16* w3t  = wt + (size_t)8 * 1048576;
    u16* w2t  = wt + (size_t)16 * 1048576;
    u16* Abuf = wt + (size_t)24 * 1048576;   // 8 MB
    u16* Ybuf = Abuf + (size_t)4096 * 1024;  // 8 MB
    u16* xb   = Ybuf + (size_t)4096 * 1024;  // 4 MB
    int*   te   = (int*)(xb + (size_t)N_TOK * DDIM);
    float* tw   = (float*)(te + 2 * N_TOK);
    int*   ptok = (int*)(tw + 2 * N_TOK);
    float* pwt  = (float*)(ptok + 2 * N_TOK);
    int*   ppos = (int*)(pwt + 2 * N_TOK);
    int*   sched = ppos + 2 * N_TOK;

    k_mega<<<dim3(16, 16, 14), 256, 0, stream>>>(x, wg, w1, w3, w2, wt, xb, d_out, te, tw);
    k_sched<<<1, 1024, 0, stream>>>(te, tw, ptok, pwt, ppos, sched);
    k_gemm13<<<dim3(16, MAXMT), 256, 0, stream>>>(xb, w1t, w3t, ptok, sched, Abuf);
    k_gemm2<<<dim3(16, MAXMT), 256, 0, stream>>>(Abuf, w2t, sched, Ybuf);
    k_combine<<<2048, 256, 0, stream>>>(Ybuf, ppos, pwt, x, d_out);
}